// Round 11
// baseline (177.759 us; speedup 1.0000x reference)
//
#include <hip/hip_runtime.h>

#define TT 18

typedef __attribute__((ext_vector_type(8))) short short8;     // 8 bf16 = 4 VGPRs
typedef __attribute__((ext_vector_type(4))) float float4_t;
typedef __attribute__((ext_vector_type(2))) float float2_t;
typedef __attribute__((ext_vector_type(2))) unsigned int uint2_t;

#if defined(__has_builtin)
#if __has_builtin(__builtin_amdgcn_exp2f)
#define FEXP2(x) __builtin_amdgcn_exp2f(x)
#else
#define FEXP2(x) exp2f(x)
#endif
#else
#define FEXP2(x) exp2f(x)
#endif

static __device__ __forceinline__ float frcp(float x){ return __builtin_amdgcn_rcpf(x); }
static __device__ __forceinline__ unsigned rne_bits(float f){
    unsigned u = __float_as_uint(f);
    return u + 0x7fffu + ((u >> 16) & 1u);
}
static __device__ __forceinline__ void bsplit(float f, unsigned &hi, unsigned &lo){
    unsigned rb = rne_bits(f);
    hi = rb >> 16;
    float fh = __uint_as_float(rb & 0xffff0000u);
    lo = rne_bits(f - fh) >> 16;
}
static __device__ __forceinline__ unsigned pack_hi16(unsigned hi_src, unsigned lo_src){
#if defined(__has_builtin)
#if __has_builtin(__builtin_amdgcn_perm)
    return __builtin_amdgcn_perm(hi_src, lo_src, 0x07060302u);
#else
    return (lo_src >> 16) | (hi_src & 0xffff0000u);
#endif
#else
    return (lo_src >> 16) | (hi_src & 0xffff0000u);
#endif
}

union U8 { short8 s; unsigned u[4]; };

#define MFMA16(A,B,C) __builtin_amdgcn_mfma_f32_16x16x32_bf16((A),(B),(C),0,0,0)

// hb ushort index with XOR bank-swizzle: group stride 256 ushorts (512B) is
// bank-aligned, so unswizzled b128 reads put all 4 quads on the SAME start
// bank (4-way alias, 4.88M conflict cycles measured r10). b' = b ^ (grp&7)
// is bijective within each group, costs 0 LDS bytes and 1 XOR, and is
// applied identically at write and read (pure addressing change — not one
// of the ledger'd latency/ordering edits).
#define HBIDX(grp, b) (((grp) * 256) + (((b) ^ ((grp) & 7)) * 8))

// chunk-2 B-frag: slots [x0h,x0l,x0h,x1h,x1l,x1h,1,1] (quad-0 lanes only).
// LEDGER — every latency/ordering modification of the r4 step regressed; do
// not retry: r3 LDS-hoist of this pack (-6%); r5 global-prefetch consumed
// top-of-step (-14%); r6 64-batch wide block (-10%); r7 head A-frag
// prefetch (-7%); r8 relaxed lgkm-only barrier + prefetch (-8%); r9
// x-from-global + smaller LDS (-8%, occupancy does NOT rise with LDS
// headroom). In-step VALU pack + in-step loads + plain __syncthreads +
// atomic epilogue (r10, +3us) = champion.
static __device__ __forceinline__ short8 make_b2f(float x0, float x1, bool q0){
    unsigned h0, l0, h1, l1;
    bsplit(x0, h0, l0);
    bsplit(x1, h1, l1);
    U8 B;
    B.u[0] = q0 ? (h0 | (l0 << 16)) : 0u;
    B.u[1] = q0 ? (h0 | (h1 << 16)) : 0u;
    B.u[2] = q0 ? (l1 | (h1 << 16)) : 0u;
    B.u[3] = q0 ? 0x3F803F80u : 0u;
    return B.s;
}

// ---------------------------------------------------------------------------
// Precompute (verified head math) + out zeroing (folded memset, saves one
// dispatch): Bhi/Blo bf16 split of Bmat[(2r+k)*18+ta][128], Cvec[48], and
// out[] = 0 so gru_mfma's atomic epilogue accumulates into clean memory.
// grid 432*256 = 110592 = 24*2*18*128 exactly; out = 393216 float4s.
// ---------------------------------------------------------------------------
__global__ __launch_bounds__(256) void head_precompute(
    const float* __restrict__ fc1_w, const float* __restrict__ fc1_b,
    const float* __restrict__ fc2_w, const float* __restrict__ fc2_b,
    unsigned short* __restrict__ Bhi, unsigned short* __restrict__ Blo,
    float* __restrict__ Cvec, float4_t* __restrict__ out4)
{
    int idx = blockIdx.x * 256 + threadIdx.x;

    // zero out: 393216 float4 = 32768*48 floats
    for (int o = idx; o < 393216; o += 110592)
        out4[o] = (float4_t){0.f, 0.f, 0.f, 0.f};

    if (idx < 24 * 2 * 18 * 128) {
        int jg = idx & 127;
        int t  = (idx >> 7) % 18;
        int k  = (idx / 2304) & 1;
        int r  = idx / 4608;
        float acc = 0.f;
        for (int c = 0; c < 24; ++c) {
            int s = t * 24 + c - r * 18;
            if (s >= 0 && s < 18) acc += fc2_w[k * 18 + s] * fc1_w[c * 128 + jg];
        }
        unsigned hi, lo;
        bsplit(acc, hi, lo);
        Bhi[idx] = (unsigned short)hi;
        Blo[idx] = (unsigned short)lo;
    }
    if (idx < 48) {
        int k = idx & 1, r = idx >> 1;
        float acc = fc2_b[k];
        for (int s = 0; s < 18; ++s)
            acc += fc2_w[k * 18 + s] * fc1_b[(r * 18 + s) % 24];
        Cvec[idx] = acc;
    }
}

// ---------------------------------------------------------------------------
// MFMA GRU, dir-split (r4 step internals, r10 atomic epilogue) + hb XOR
// bank-swizzle (this round): ONE block = 32 batches, ONE direction, 4 waves
// (wave = jq = gate column group). Step internals identical to the 106-107us
// champion; the ONLY change is HBIDX() swizzled addressing on the hb h-state
// buffer (writes and reads use the same bijection), targeting the 4.88M
// SQ_LDS_BANK_CONFLICT cycles (~7% of runtime).
// LDS = 16384 (hb) + 4608 (x_s) + 6144 (out_acc) = 27136 -> 6 blocks/CU.
// ---------------------------------------------------------------------------
struct SMs {
    alignas(16) unsigned short hb[2][2][2048]; // 16 KiB [parity][hi/lo][HBIDX(grp,b)+j7]
    float2_t x_s[32][18];                      // 4.5 KiB, read-only after init
    float out_acc[48][32];                     // 6 KiB [cell][b] (transposed)
};

__global__ __launch_bounds__(256, 4) void gru_mfma(
    const float* __restrict__ x,
    const float* __restrict__ w_ih_f, const float* __restrict__ w_hh_f,
    const float* __restrict__ b_ih_f, const float* __restrict__ b_hh_f,
    const float* __restrict__ w_ih_b, const float* __restrict__ w_hh_b,
    const float* __restrict__ b_ih_b, const float* __restrict__ b_hh_b,
    const unsigned short* __restrict__ Bhi, const unsigned short* __restrict__ Blo,
    const float* __restrict__ Cvec, float* __restrict__ out)
{
    __shared__ SMs sm;
    const int tid  = threadIdx.x;
    const int lane = tid & 63;
    const int jq   = tid >> 6;            // wave index = gate column group
    const int dir  = blockIdx.x & 1;
    const int bb   = (blockIdx.x >> 1) * 32;
    const int col  = lane & 15;
    const int quad = lane >> 4;
    const bool q0  = (quad == 0);

    const float* __restrict__ wih = dir ? w_ih_b : w_ih_f;
    const float* __restrict__ whh = dir ? w_hh_b : w_hh_f;
    const float* __restrict__ bih = dir ? b_ih_b : b_ih_f;
    const float* __restrict__ bhh = dir ? b_hh_b : b_hh_f;

    const float L1 = 1.4426950408889634f;   // log2(e)
    const float L2 = 2.8853900817779268f;   // 2*log2(e)

    // ---- zero parity-1 h planes (swizzle is bijective: linear zero OK) ----
    {
        unsigned* z = (unsigned*)&sm.hb[1][0][0];   // 8 KiB = 2048 uints
        #pragma unroll
        for (int o = 0; o < 8; ++o) z[tid + o * 256] = 0u;
    }
    for (int o = tid; o < 48 * 32; o += 256) ((float*)sm.out_acc)[o] = 0.f;

    // ---- stage x (read-only after the barrier) ----
    for (int p = tid; p < 32 * 18; p += 256) {
        int b = p / 18, t = p % 18;
        sm.x_s[b][t] = *(const float2_t*)(x + (size_t)(bb + b) * 36 + t * 2);
    }

    // ---- persistent W A-frags (RNE bf16, log2e-scaled): r,z by L1; nh by L2 ----
    short8 wf[3][2];
    #pragma unroll
    for (int ty = 0; ty < 3; ++ty) {
        float sc = (ty == 2) ? L2 : L1;
        int g = ty * 64 + jq * 16 + col;
        #pragma unroll
        for (int c = 0; c < 2; ++c) {
            const float* p = whh + g * 64 + c * 32 + quad * 8;
            float4_t f0 = *(const float4_t*)p;
            float4_t f1 = *(const float4_t*)(p + 4);
            short8 s;
            #pragma unroll
            for (int e = 0; e < 8; ++e) {
                float f = (e < 4) ? f0[e] : f1[e - 4];
                s[e] = (short)(rne_bits(sc * f) >> 16);
            }
            wf[ty][c] = s;
        }
    }

    // ---- chunk-2 A-frags in registers (real data on quad-0 lanes only) ----
    short8 c2[4];
    {
        int g0 = jq * 16 + col;
        #pragma unroll
        for (int ty = 0; ty < 2; ++ty) {      // r, z
            int g = ty * 64 + g0;
            unsigned w0h, w0l, w1h, w1l, bh, bl;
            bsplit(L1 * wih[2 * g],     w0h, w0l);
            bsplit(L1 * wih[2 * g + 1], w1h, w1l);
            bsplit(L1 * (bih[g] + bhh[g]), bh, bl);
            U8 f;
            f.u[0] = q0 ? (w0h | (w0h << 16)) : 0u;
            f.u[1] = q0 ? (w0l | (w1h << 16)) : 0u;
            f.u[2] = q0 ? (w1h | (w1l << 16)) : 0u;
            f.u[3] = q0 ? (bh  | (bl  << 16)) : 0u;
            c2[ty] = f.s;
        }
        {   // nh: h-side bias only
            unsigned bh, bl;
            bsplit(L2 * bhh[128 + g0], bh, bl);
            U8 f;
            f.u[0] = 0u; f.u[1] = 0u; f.u[2] = 0u;
            f.u[3] = q0 ? (bh | (bl << 16)) : 0u;
            c2[2] = f.s;
        }
        {   // nx
            int g = 128 + g0;
            unsigned w0h, w0l, w1h, w1l, bh, bl;
            bsplit(L2 * wih[2 * g],     w0h, w0l);
            bsplit(L2 * wih[2 * g + 1], w1h, w1l);
            bsplit(L2 * bih[g], bh, bl);
            U8 f;
            f.u[0] = q0 ? (w0h | (w0h << 16)) : 0u;
            f.u[1] = q0 ? (w0l | (w1h << 16)) : 0u;
            f.u[2] = q0 ? (w1h | (w1l << 16)) : 0u;
            f.u[3] = q0 ? (bh  | (bl  << 16)) : 0u;
            c2[3] = f.s;
        }
    }

    float hprev[8] = {0.f,0.f,0.f,0.f,0.f,0.f,0.f,0.f};

    __syncthreads();

    auto step = [&](int t, int pr, int pw) {
        const bool myturn = (t > 0) && (((t - 1) & 3) == jq);
        const int tx = dir ? (TT - 1 - t) : t;

        // (1) h-hi B-frags, both N-tiles (swizzled addressing)
        short8 h0c0 = *(const short8*)&sm.hb[pr][0][HBIDX(quad,     col)];
        short8 h0c1 = *(const short8*)&sm.hb[pr][0][HBIDX(4 + quad, col)];
        short8 h1c0 = *(const short8*)&sm.hb[pr][0][HBIDX(quad,     16 + col)];
        short8 h1c1 = *(const short8*)&sm.hb[pr][0][HBIDX(4 + quad, 16 + col)];

        // (2) chunk-2 B-frags from the read-only x stage (VALU pack, overlaps)
        float2_t xv0 = sm.x_s[col][tx];
        float2_t xv1 = sm.x_s[16 + col][tx];
        short8 b2f0 = make_b2f(xv0[0], xv0[1], q0);
        short8 b2f1 = make_b2f(xv1[0], xv1[1], q0);

        // (3) head loads (turn wave only): Bhi/Blo from global + h-lo frags
        short8 hA0, hA1, lA0, lA1, l0c0, l0c1, l1c0, l1c1;
        int base_h = 0;
        if (myturn) {
            int s  = t - 1;
            int ta = dir ? (TT - 1 - s) : s;
            base_h = 4 * (ta / 3) + ta % 3;
            int i  = col & 3;
            int rr = base_h + (i >> 1);
            int kk = i & 1;
            size_t boff = (size_t)((rr * 2 + kk) * TT + ta) * 128 + dir * 64 + quad * 8;
            hA0 = *(const short8*)(Bhi + boff);
            hA1 = *(const short8*)(Bhi + boff + 32);
            lA0 = *(const short8*)(Blo + boff);
            lA1 = *(const short8*)(Blo + boff + 32);
            l0c0 = *(const short8*)&sm.hb[pr][1][HBIDX(quad,     col)];
            l0c1 = *(const short8*)&sm.hb[pr][1][HBIDX(4 + quad, col)];
            l1c0 = *(const short8*)&sm.hb[pr][1][HBIDX(quad,     16 + col)];
            l1c1 = *(const short8*)&sm.hb[pr][1][HBIDX(4 + quad, 16 + col)];
        }

        // (4) gate GEMM + elementwise per N-tile; head between the tiles
        #pragma unroll
        for (int nt = 0; nt < 2; ++nt) {
            short8 hc0 = nt ? h1c0 : h0c0;
            short8 hc1 = nt ? h1c1 : h0c1;
            short8 b2f = nt ? b2f1 : b2f0;
            float4_t aR  = (float4_t){0.f,0.f,0.f,0.f};
            float4_t aZ  = (float4_t){0.f,0.f,0.f,0.f};
            float4_t aNH = (float4_t){0.f,0.f,0.f,0.f};
            float4_t aNX = (float4_t){0.f,0.f,0.f,0.f};
            aR  = MFMA16(wf[0][0], hc0, aR);
            aR  = MFMA16(wf[0][1], hc1, aR);
            aR  = MFMA16(c2[0],    b2f, aR);
            aZ  = MFMA16(wf[1][0], hc0, aZ);
            aZ  = MFMA16(wf[1][1], hc1, aZ);
            aZ  = MFMA16(c2[1],    b2f, aZ);
            aNH = MFMA16(wf[2][0], hc0, aNH);
            aNH = MFMA16(wf[2][1], hc1, aNH);
            aNH = MFMA16(c2[2],    b2f, aNH);
            aNX = MFMA16(c2[3],    b2f, aNX);

            unsigned rh[4], rl[4];
            #pragma unroll
            for (int reg = 0; reg < 4; ++reg) {
                float r = frcp(1.f + FEXP2(-aR[reg]));
                float z = frcp(1.f + FEXP2(-aZ[reg]));
                float a = fmaf(r, aNH[reg], aNX[reg]);
                float n = fmaf(2.f, frcp(1.f + FEXP2(-a)), -1.f);
                float hnew = fmaf(z, hprev[nt * 4 + reg] - n, n);
                hprev[nt * 4 + reg] = hnew;
                unsigned rb = rne_bits(hnew);
                rh[reg] = rb;
                rl[reg] = __float_as_uint(hnew - __uint_as_float(rb & 0xffff0000u));
            }
            int grpw = jq * 2 + (quad >> 1);
            int woff = HBIDX(grpw, nt * 16 + col) + (quad & 1) * 4;
            uint2_t dh, dl;
            dh[0] = pack_hi16(rh[1], rh[0]);
            dh[1] = pack_hi16(rh[3], rh[2]);
            dl[0] = pack_hi16(rl[1], rl[0]);
            dl[1] = pack_hi16(rl[3], rl[2]);
            *(uint2_t*)&sm.hb[pw][0][woff] = dh;
            *(uint2_t*)&sm.hb[pw][1][woff] = dl;

            if (nt == 0 && myturn) {
                float4_t a0 = (float4_t){0.f,0.f,0.f,0.f};
                a0 = MFMA16(hA0, h0c0, a0);
                a0 = MFMA16(hA1, h0c1, a0);
                a0 = MFMA16(hA0, l0c0, a0);
                a0 = MFMA16(hA1, l0c1, a0);
                a0 = MFMA16(lA0, h0c0, a0);
                a0 = MFMA16(lA1, h0c1, a0);
                float4_t a1 = (float4_t){0.f,0.f,0.f,0.f};
                a1 = MFMA16(hA0, h1c0, a1);
                a1 = MFMA16(hA1, h1c1, a1);
                a1 = MFMA16(hA0, l1c0, a1);
                a1 = MFMA16(hA1, l1c1, a1);
                a1 = MFMA16(lA0, h1c0, a1);
                a1 = MFMA16(lA1, h1c1, a1);
                if (q0) {
                    #pragma unroll
                    for (int reg = 0; reg < 4; ++reg) {
                        int cell = (base_h + (reg >> 1)) * 2 + (reg & 1);
                        sm.out_acc[cell][col]      += a0[reg];
                        sm.out_acc[cell][16 + col] += a1[reg];
                    }
                }
            }
        }

        __syncthreads();
    };

    #pragma unroll 1
    for (int tt = 0; tt < 9; ++tt) {
        step(2 * tt,     1, 0);
        step(2 * tt + 1, 0, 1);
    }

    // ---- final head for s = 17 (h17 in parity 1), jq == 1 wave ----
    if (jq == ((TT - 1) & 3)) {
        int ta = dir ? 0 : (TT - 1);
        int base_h = 4 * (ta / 3) + ta % 3;
        int i  = col & 3;
        int rr = base_h + (i >> 1);
        int kk = i & 1;
        size_t boff = (size_t)((rr * 2 + kk) * TT + ta) * 128 + dir * 64 + quad * 8;
        short8 hA0 = *(const short8*)(Bhi + boff);
        short8 hA1 = *(const short8*)(Bhi + boff + 32);
        short8 lA0 = *(const short8*)(Blo + boff);
        short8 lA1 = *(const short8*)(Blo + boff + 32);
        #pragma unroll
        for (int nt = 0; nt < 2; ++nt) {
            short8 hc0 = *(const short8*)&sm.hb[1][0][HBIDX(quad,     nt * 16 + col)];
            short8 hc1 = *(const short8*)&sm.hb[1][0][HBIDX(4 + quad, nt * 16 + col)];
            short8 lc0 = *(const short8*)&sm.hb[1][1][HBIDX(quad,     nt * 16 + col)];
            short8 lc1 = *(const short8*)&sm.hb[1][1][HBIDX(4 + quad, nt * 16 + col)];
            float4_t acch = (float4_t){0.f,0.f,0.f,0.f};
            acch = MFMA16(hA0, hc0, acch);
            acch = MFMA16(hA1, hc1, acch);
            acch = MFMA16(hA0, lc0, acch);
            acch = MFMA16(hA1, lc1, acch);
            acch = MFMA16(lA0, hc0, acch);
            acch = MFMA16(lA1, hc1, acch);
            if (q0) {
                #pragma unroll
                for (int reg = 0; reg < 4; ++reg) {
                    int cell = (base_h + (reg >> 1)) * 2 + (reg & 1);
                    sm.out_acc[cell][nt * 16 + col] += acch[reg];
                }
            }
        }
    }
    __syncthreads();

    // ---- epilogue: both dirs atomicAdd into pre-zeroed out. Exactly two
    //      fp addends per cell (commutative) -> bitwise identical result
    //      in either arrival order. ----
    float* __restrict__ dst = out + (size_t)bb * 48;
    #pragma unroll
    for (int rep = 0; rep < 6; ++rep) {
        int o = rep * 256 + tid;          // 1536 = 32 b * 48 cells
        int b = o / 48, c = o % 48;
        float v = sm.out_acc[c][b];
        if (!dir) v += Cvec[c];
        atomicAdd(dst + o, v);
    }
}

extern "C" void kernel_launch(void* const* d_in, const int* in_sizes, int n_in,
                              void* d_out, int out_size, void* d_ws, size_t ws_size,
                              hipStream_t stream) {
    const float* x      = (const float*)d_in[0];
    const float* w_ih_f = (const float*)d_in[1];
    const float* w_hh_f = (const float*)d_in[2];
    const float* b_ih_f = (const float*)d_in[3];
    const float* b_hh_f = (const float*)d_in[4];
    const float* w_ih_b = (const float*)d_in[5];
    const float* w_hh_b = (const float*)d_in[6];
    const float* b_ih_b = (const float*)d_in[7];
    const float* b_hh_b = (const float*)d_in[8];
    const float* fc1_w  = (const float*)d_in[9];
    const float* fc1_b  = (const float*)d_in[10];
    const float* fc2_w  = (const float*)d_in[11];
    const float* fc2_b  = (const float*)d_in[12];
    float* out  = (float*)d_out;

    // ws layout: Cvec 256B | Bhi 221184B | Blo 221184B
    float*          Cvec  = (float*)d_ws;
    unsigned short* Bhi   = (unsigned short*)((char*)d_ws + 256);
    unsigned short* Blo   = Bhi + 110592;

    head_precompute<<<432, 256, 0, stream>>>(fc1_w, fc1_b, fc2_w, fc2_b,
                                             Bhi, Blo, Cvec, (float4_t*)out);
    gru_mfma<<<2048, 256, 0, stream>>>(x, w_ih_f, w_hh_f, b_ih_f, b_hh_f,
                                       w_ih_b, w_hh_b, b_ih_b, b_hh_b,
                                       Bhi, Blo, Cvec, out);
}

// Round 12
// 175.083 us; speedup vs baseline: 1.0153x; 1.0153x over previous
//
#include <hip/hip_runtime.h>

#define TT 18

typedef __attribute__((ext_vector_type(8))) short short8;     // 8 bf16 = 4 VGPRs
typedef __attribute__((ext_vector_type(4))) float float4_t;
typedef __attribute__((ext_vector_type(2))) float float2_t;
typedef __attribute__((ext_vector_type(2))) unsigned int uint2_t;

#if defined(__has_builtin)
#if __has_builtin(__builtin_amdgcn_exp2f)
#define FEXP2(x) __builtin_amdgcn_exp2f(x)
#else
#define FEXP2(x) exp2f(x)
#endif
#else
#define FEXP2(x) exp2f(x)
#endif

static __device__ __forceinline__ float frcp(float x){ return __builtin_amdgcn_rcpf(x); }
static __device__ __forceinline__ unsigned rne_bits(float f){
    unsigned u = __float_as_uint(f);
    return u + 0x7fffu + ((u >> 16) & 1u);
}
static __device__ __forceinline__ void bsplit(float f, unsigned &hi, unsigned &lo){
    unsigned rb = rne_bits(f);
    hi = rb >> 16;
    float fh = __uint_as_float(rb & 0xffff0000u);
    lo = rne_bits(f - fh) >> 16;
}
static __device__ __forceinline__ unsigned pack_hi16(unsigned hi_src, unsigned lo_src){
#if defined(__has_builtin)
#if __has_builtin(__builtin_amdgcn_perm)
    return __builtin_amdgcn_perm(hi_src, lo_src, 0x07060302u);
#else
    return (lo_src >> 16) | (hi_src & 0xffff0000u);
#endif
#else
    return (lo_src >> 16) | (hi_src & 0xffff0000u);
#endif
}

union U8 { short8 s; unsigned u[4]; };

#define MFMA16(A,B,C) __builtin_amdgcn_mfma_f32_16x16x32_bf16((A),(B),(C),0,0,0)

// chunk-2 B-frag: slots [x0h,x0l,x0h,x1h,x1l,x1h,1,1] (quad-0 lanes only).
// LEDGER — every modification of the r4 step internals regressed; do not
// retry: r3 LDS-hoist of this pack (-6%); r5 global-prefetch consumed
// top-of-step (-14%); r6 64-batch wide block (-10%); r7 head A-frag
// prefetch (-7%); r8 relaxed lgkm-only barrier + prefetch (-8%); r9
// x-from-global + smaller LDS (-8%, occupancy does NOT rise with LDS
// headroom); r11 hb XOR bank-swizzle (conflicts EXACTLY unchanged at
// 4882432 — a structural constant of b128/wave64 access here, present in
// every 256-thread variant incl. no-x_s r9 — and -3% from address VALU).
// In-step VALU pack + in-step loads + plain __syncthreads + linear hb +
// atomic epilogue (r10) = champion at 106us.
static __device__ __forceinline__ short8 make_b2f(float x0, float x1, bool q0){
    unsigned h0, l0, h1, l1;
    bsplit(x0, h0, l0);
    bsplit(x1, h1, l1);
    U8 B;
    B.u[0] = q0 ? (h0 | (l0 << 16)) : 0u;
    B.u[1] = q0 ? (h0 | (h1 << 16)) : 0u;
    B.u[2] = q0 ? (l1 | (h1 << 16)) : 0u;
    B.u[3] = q0 ? 0x3F803F80u : 0u;
    return B.s;
}

// ---------------------------------------------------------------------------
// Precompute (verified head math) + out zeroing (folded memset, r11-proven
// correct): Bhi/Blo bf16 split of Bmat[(2r+k)*18+ta][128], Cvec[48], and
// out[] = 0 so gru_mfma's atomic epilogue accumulates into clean memory.
// grid 432*256 = 110592 = 24*2*18*128 exactly; out = 393216 float4s.
// ---------------------------------------------------------------------------
__global__ __launch_bounds__(256) void head_precompute(
    const float* __restrict__ fc1_w, const float* __restrict__ fc1_b,
    const float* __restrict__ fc2_w, const float* __restrict__ fc2_b,
    unsigned short* __restrict__ Bhi, unsigned short* __restrict__ Blo,
    float* __restrict__ Cvec, float4_t* __restrict__ out4)
{
    int idx = blockIdx.x * 256 + threadIdx.x;

    // zero out: 393216 float4 = 32768*48 floats
    for (int o = idx; o < 393216; o += 110592)
        out4[o] = (float4_t){0.f, 0.f, 0.f, 0.f};

    if (idx < 24 * 2 * 18 * 128) {
        int jg = idx & 127;
        int t  = (idx >> 7) % 18;
        int k  = (idx / 2304) & 1;
        int r  = idx / 4608;
        float acc = 0.f;
        for (int c = 0; c < 24; ++c) {
            int s = t * 24 + c - r * 18;
            if (s >= 0 && s < 18) acc += fc2_w[k * 18 + s] * fc1_w[c * 128 + jg];
        }
        unsigned hi, lo;
        bsplit(acc, hi, lo);
        Bhi[idx] = (unsigned short)hi;
        Blo[idx] = (unsigned short)lo;
    }
    if (idx < 48) {
        int k = idx & 1, r = idx >> 1;
        float acc = fc2_b[k];
        for (int s = 0; s < 18; ++s)
            acc += fc2_w[k * 18 + s] * fc1_b[(r * 18 + s) % 24];
        Cvec[idx] = acc;
    }
}

// ---------------------------------------------------------------------------
// MFMA GRU, dir-split (r4 step internals VERBATIM, r10 atomic epilogue):
// ONE block = 32 batches, ONE direction, 4 waves (wave = jq = gate column
// group). In-step make_b2f, in-step Bhi/Blo head loads, LDS x stage, plain
// __syncthreads, LINEAR hb addressing. Epilogue: both dirs atomicAdd into
// pre-zeroed out (exactly two commutative fp addends/cell -> bitwise
// deterministic). LDS = 16384 + 4608 + 6144 = 27136 -> 6 blocks/CU.
// ---------------------------------------------------------------------------
struct SMs {
    alignas(16) unsigned short hb[2][2][2048]; // 16 KiB [parity][hi/lo][(j>>3)*256+b*8+(j&7)]
    float2_t x_s[32][18];                      // 4.5 KiB, read-only after init
    float out_acc[48][32];                     // 6 KiB [cell][b] (transposed)
};

__global__ __launch_bounds__(256, 4) void gru_mfma(
    const float* __restrict__ x,
    const float* __restrict__ w_ih_f, const float* __restrict__ w_hh_f,
    const float* __restrict__ b_ih_f, const float* __restrict__ b_hh_f,
    const float* __restrict__ w_ih_b, const float* __restrict__ w_hh_b,
    const float* __restrict__ b_ih_b, const float* __restrict__ b_hh_b,
    const unsigned short* __restrict__ Bhi, const unsigned short* __restrict__ Blo,
    const float* __restrict__ Cvec, float* __restrict__ out)
{
    __shared__ SMs sm;
    const int tid  = threadIdx.x;
    const int lane = tid & 63;
    const int jq   = tid >> 6;            // wave index = gate column group
    const int dir  = blockIdx.x & 1;
    const int bb   = (blockIdx.x >> 1) * 32;
    const int col  = lane & 15;
    const int quad = lane >> 4;
    const bool q0  = (quad == 0);

    const float* __restrict__ wih = dir ? w_ih_b : w_ih_f;
    const float* __restrict__ whh = dir ? w_hh_b : w_hh_f;
    const float* __restrict__ bih = dir ? b_ih_b : b_ih_f;
    const float* __restrict__ bhh = dir ? b_hh_b : b_hh_f;

    const float L1 = 1.4426950408889634f;   // log2(e)
    const float L2 = 2.8853900817779268f;   // 2*log2(e)

    // ---- zero parity-1 h planes and out_acc ----
    {
        unsigned* z = (unsigned*)&sm.hb[1][0][0];   // 8 KiB = 2048 uints
        #pragma unroll
        for (int o = 0; o < 8; ++o) z[tid + o * 256] = 0u;
    }
    for (int o = tid; o < 48 * 32; o += 256) ((float*)sm.out_acc)[o] = 0.f;

    // ---- stage x (read-only after the barrier) ----
    for (int p = tid; p < 32 * 18; p += 256) {
        int b = p / 18, t = p % 18;
        sm.x_s[b][t] = *(const float2_t*)(x + (size_t)(bb + b) * 36 + t * 2);
    }

    // ---- persistent W A-frags (RNE bf16, log2e-scaled): r,z by L1; nh by L2 ----
    short8 wf[3][2];
    #pragma unroll
    for (int ty = 0; ty < 3; ++ty) {
        float sc = (ty == 2) ? L2 : L1;
        int g = ty * 64 + jq * 16 + col;
        #pragma unroll
        for (int c = 0; c < 2; ++c) {
            const float* p = whh + g * 64 + c * 32 + quad * 8;
            float4_t f0 = *(const float4_t*)p;
            float4_t f1 = *(const float4_t*)(p + 4);
            short8 s;
            #pragma unroll
            for (int e = 0; e < 8; ++e) {
                float f = (e < 4) ? f0[e] : f1[e - 4];
                s[e] = (short)(rne_bits(sc * f) >> 16);
            }
            wf[ty][c] = s;
        }
    }

    // ---- chunk-2 A-frags in registers (real data on quad-0 lanes only) ----
    short8 c2[4];
    {
        int g0 = jq * 16 + col;
        #pragma unroll
        for (int ty = 0; ty < 2; ++ty) {      // r, z
            int g = ty * 64 + g0;
            unsigned w0h, w0l, w1h, w1l, bh, bl;
            bsplit(L1 * wih[2 * g],     w0h, w0l);
            bsplit(L1 * wih[2 * g + 1], w1h, w1l);
            bsplit(L1 * (bih[g] + bhh[g]), bh, bl);
            U8 f;
            f.u[0] = q0 ? (w0h | (w0h << 16)) : 0u;
            f.u[1] = q0 ? (w0l | (w1h << 16)) : 0u;
            f.u[2] = q0 ? (w1h | (w1l << 16)) : 0u;
            f.u[3] = q0 ? (bh  | (bl  << 16)) : 0u;
            c2[ty] = f.s;
        }
        {   // nh: h-side bias only
            unsigned bh, bl;
            bsplit(L2 * bhh[128 + g0], bh, bl);
            U8 f;
            f.u[0] = 0u; f.u[1] = 0u; f.u[2] = 0u;
            f.u[3] = q0 ? (bh | (bl << 16)) : 0u;
            c2[2] = f.s;
        }
        {   // nx
            int g = 128 + g0;
            unsigned w0h, w0l, w1h, w1l, bh, bl;
            bsplit(L2 * wih[2 * g],     w0h, w0l);
            bsplit(L2 * wih[2 * g + 1], w1h, w1l);
            bsplit(L2 * bih[g], bh, bl);
            U8 f;
            f.u[0] = q0 ? (w0h | (w0h << 16)) : 0u;
            f.u[1] = q0 ? (w0l | (w1h << 16)) : 0u;
            f.u[2] = q0 ? (w1h | (w1l << 16)) : 0u;
            f.u[3] = q0 ? (bh  | (bl  << 16)) : 0u;
            c2[3] = f.s;
        }
    }

    float hprev[8] = {0.f,0.f,0.f,0.f,0.f,0.f,0.f,0.f};

    __syncthreads();

    auto step = [&](int t, int pr, int pw) {
        const bool myturn = (t > 0) && (((t - 1) & 3) == jq);
        const int tx = dir ? (TT - 1 - t) : t;

        // (1) h-hi B-frags, both N-tiles
        short8 h0c0 = *(const short8*)&sm.hb[pr][0][quad * 256 + col * 8];
        short8 h0c1 = *(const short8*)&sm.hb[pr][0][(4 + quad) * 256 + col * 8];
        short8 h1c0 = *(const short8*)&sm.hb[pr][0][quad * 256 + (16 + col) * 8];
        short8 h1c1 = *(const short8*)&sm.hb[pr][0][(4 + quad) * 256 + (16 + col) * 8];

        // (2) chunk-2 B-frags from the read-only x stage (VALU pack, overlaps)
        float2_t xv0 = sm.x_s[col][tx];
        float2_t xv1 = sm.x_s[16 + col][tx];
        short8 b2f0 = make_b2f(xv0[0], xv0[1], q0);
        short8 b2f1 = make_b2f(xv1[0], xv1[1], q0);

        // (3) head loads (turn wave only): Bhi/Blo from global + h-lo frags
        short8 hA0, hA1, lA0, lA1, l0c0, l0c1, l1c0, l1c1;
        int base_h = 0;
        if (myturn) {
            int s  = t - 1;
            int ta = dir ? (TT - 1 - s) : s;
            base_h = 4 * (ta / 3) + ta % 3;
            int i  = col & 3;
            int rr = base_h + (i >> 1);
            int kk = i & 1;
            size_t boff = (size_t)((rr * 2 + kk) * TT + ta) * 128 + dir * 64 + quad * 8;
            hA0 = *(const short8*)(Bhi + boff);
            hA1 = *(const short8*)(Bhi + boff + 32);
            lA0 = *(const short8*)(Blo + boff);
            lA1 = *(const short8*)(Blo + boff + 32);
            l0c0 = *(const short8*)&sm.hb[pr][1][quad * 256 + col * 8];
            l0c1 = *(const short8*)&sm.hb[pr][1][(4 + quad) * 256 + col * 8];
            l1c0 = *(const short8*)&sm.hb[pr][1][quad * 256 + (16 + col) * 8];
            l1c1 = *(const short8*)&sm.hb[pr][1][(4 + quad) * 256 + (16 + col) * 8];
        }

        // (4) gate GEMM + elementwise per N-tile; head between the tiles
        #pragma unroll
        for (int nt = 0; nt < 2; ++nt) {
            short8 hc0 = nt ? h1c0 : h0c0;
            short8 hc1 = nt ? h1c1 : h0c1;
            short8 b2f = nt ? b2f1 : b2f0;
            float4_t aR  = (float4_t){0.f,0.f,0.f,0.f};
            float4_t aZ  = (float4_t){0.f,0.f,0.f,0.f};
            float4_t aNH = (float4_t){0.f,0.f,0.f,0.f};
            float4_t aNX = (float4_t){0.f,0.f,0.f,0.f};
            aR  = MFMA16(wf[0][0], hc0, aR);
            aR  = MFMA16(wf[0][1], hc1, aR);
            aR  = MFMA16(c2[0],    b2f, aR);
            aZ  = MFMA16(wf[1][0], hc0, aZ);
            aZ  = MFMA16(wf[1][1], hc1, aZ);
            aZ  = MFMA16(c2[1],    b2f, aZ);
            aNH = MFMA16(wf[2][0], hc0, aNH);
            aNH = MFMA16(wf[2][1], hc1, aNH);
            aNH = MFMA16(c2[2],    b2f, aNH);
            aNX = MFMA16(c2[3],    b2f, aNX);

            unsigned rh[4], rl[4];
            #pragma unroll
            for (int reg = 0; reg < 4; ++reg) {
                float r = frcp(1.f + FEXP2(-aR[reg]));
                float z = frcp(1.f + FEXP2(-aZ[reg]));
                float a = fmaf(r, aNH[reg], aNX[reg]);
                float n = fmaf(2.f, frcp(1.f + FEXP2(-a)), -1.f);
                float hnew = fmaf(z, hprev[nt * 4 + reg] - n, n);
                hprev[nt * 4 + reg] = hnew;
                unsigned rb = rne_bits(hnew);
                rh[reg] = rb;
                rl[reg] = __float_as_uint(hnew - __uint_as_float(rb & 0xffff0000u));
            }
            int woff = (jq * 2 + (quad >> 1)) * 256 + (nt * 16 + col) * 8 + (quad & 1) * 4;
            uint2_t dh, dl;
            dh[0] = pack_hi16(rh[1], rh[0]);
            dh[1] = pack_hi16(rh[3], rh[2]);
            dl[0] = pack_hi16(rl[1], rl[0]);
            dl[1] = pack_hi16(rl[3], rl[2]);
            *(uint2_t*)&sm.hb[pw][0][woff] = dh;
            *(uint2_t*)&sm.hb[pw][1][woff] = dl;

            if (nt == 0 && myturn) {
                float4_t a0 = (float4_t){0.f,0.f,0.f,0.f};
                a0 = MFMA16(hA0, h0c0, a0);
                a0 = MFMA16(hA1, h0c1, a0);
                a0 = MFMA16(hA0, l0c0, a0);
                a0 = MFMA16(hA1, l0c1, a0);
                a0 = MFMA16(lA0, h0c0, a0);
                a0 = MFMA16(lA1, h0c1, a0);
                float4_t a1 = (float4_t){0.f,0.f,0.f,0.f};
                a1 = MFMA16(hA0, h1c0, a1);
                a1 = MFMA16(hA1, h1c1, a1);
                a1 = MFMA16(hA0, l1c0, a1);
                a1 = MFMA16(hA1, l1c1, a1);
                a1 = MFMA16(lA0, h1c0, a1);
                a1 = MFMA16(lA1, h1c1, a1);
                if (q0) {
                    #pragma unroll
                    for (int reg = 0; reg < 4; ++reg) {
                        int cell = (base_h + (reg >> 1)) * 2 + (reg & 1);
                        sm.out_acc[cell][col]      += a0[reg];
                        sm.out_acc[cell][16 + col] += a1[reg];
                    }
                }
            }
        }

        __syncthreads();
    };

    #pragma unroll 1
    for (int tt = 0; tt < 9; ++tt) {
        step(2 * tt,     1, 0);
        step(2 * tt + 1, 0, 1);
    }

    // ---- final head for s = 17 (h17 in parity 1), jq == 1 wave ----
    if (jq == ((TT - 1) & 3)) {
        int ta = dir ? 0 : (TT - 1);
        int base_h = 4 * (ta / 3) + ta % 3;
        int i  = col & 3;
        int rr = base_h + (i >> 1);
        int kk = i & 1;
        size_t boff = (size_t)((rr * 2 + kk) * TT + ta) * 128 + dir * 64 + quad * 8;
        short8 hA0 = *(const short8*)(Bhi + boff);
        short8 hA1 = *(const short8*)(Bhi + boff + 32);
        short8 lA0 = *(const short8*)(Blo + boff);
        short8 lA1 = *(const short8*)(Blo + boff + 32);
        #pragma unroll
        for (int nt = 0; nt < 2; ++nt) {
            short8 hc0 = *(const short8*)&sm.hb[1][0][quad * 256 + (nt * 16 + col) * 8];
            short8 hc1 = *(const short8*)&sm.hb[1][0][(4 + quad) * 256 + (nt * 16 + col) * 8];
            short8 lc0 = *(const short8*)&sm.hb[1][1][quad * 256 + (nt * 16 + col) * 8];
            short8 lc1 = *(const short8*)&sm.hb[1][1][(4 + quad) * 256 + (nt * 16 + col) * 8];
            float4_t acch = (float4_t){0.f,0.f,0.f,0.f};
            acch = MFMA16(hA0, hc0, acch);
            acch = MFMA16(hA1, hc1, acch);
            acch = MFMA16(hA0, lc0, acch);
            acch = MFMA16(hA1, lc1, acch);
            acch = MFMA16(lA0, hc0, acch);
            acch = MFMA16(lA1, hc1, acch);
            if (q0) {
                #pragma unroll
                for (int reg = 0; reg < 4; ++reg) {
                    int cell = (base_h + (reg >> 1)) * 2 + (reg & 1);
                    sm.out_acc[cell][nt * 16 + col] += acch[reg];
                }
            }
        }
    }
    __syncthreads();

    // ---- epilogue: both dirs atomicAdd into pre-zeroed out. Exactly two
    //      fp addends per cell (commutative) -> bitwise identical result
    //      in either arrival order. ----
    float* __restrict__ dst = out + (size_t)bb * 48;
    #pragma unroll
    for (int rep = 0; rep < 6; ++rep) {
        int o = rep * 256 + tid;          // 1536 = 32 b * 48 cells
        int b = o / 48, c = o % 48;
        float v = sm.out_acc[c][b];
        if (!dir) v += Cvec[c];
        atomicAdd(dst + o, v);
    }
}

extern "C" void kernel_launch(void* const* d_in, const int* in_sizes, int n_in,
                              void* d_out, int out_size, void* d_ws, size_t ws_size,
                              hipStream_t stream) {
    const float* x      = (const float*)d_in[0];
    const float* w_ih_f = (const float*)d_in[1];
    const float* w_hh_f = (const float*)d_in[2];
    const float* b_ih_f = (const float*)d_in[3];
    const float* b_hh_f = (const float*)d_in[4];
    const float* w_ih_b = (const float*)d_in[5];
    const float* w_hh_b = (const float*)d_in[6];
    const float* b_ih_b = (const float*)d_in[7];
    const float* b_hh_b = (const float*)d_in[8];
    const float* fc1_w  = (const float*)d_in[9];
    const float* fc1_b  = (const float*)d_in[10];
    const float* fc2_w  = (const float*)d_in[11];
    const float* fc2_b  = (const float*)d_in[12];
    float* out  = (float*)d_out;

    // ws layout: Cvec 256B | Bhi 221184B | Blo 221184B
    float*          Cvec  = (float*)d_ws;
    unsigned short* Bhi   = (unsigned short*)((char*)d_ws + 256);
    unsigned short* Blo   = Bhi + 110592;

    head_precompute<<<432, 256, 0, stream>>>(fc1_w, fc1_b, fc2_w, fc2_b,
                                             Bhi, Blo, Cvec, (float4_t*)out);
    gru_mfma<<<2048, 256, 0, stream>>>(x, w_ih_f, w_hh_f, b_ih_f, b_hh_f,
                                       w_ih_b, w_hh_b, b_ih_b, b_hh_b,
                                       Bhi, Blo, Cvec, out);
}